// Round 2
// baseline (10047.365 us; speedup 1.0000x reference)
//
#include <hip/hip_runtime.h>

#define N_NODES 100000
#define N_EDGES 3200000
#define N_FEAT 512
#define HIDDEN 16
#define N_CLASSES 40

// ---------------- zero / init helpers ----------------

__global__ void k_zero(float* p, int n) {
    int i = blockIdx.x * 256 + threadIdx.x;
    if (i < n) p[i] = 0.0f;
}

__global__ void k_init_deg(float* deg) {
    int i = blockIdx.x * 256 + threadIdx.x;
    if (i < N_NODES) deg[i] = 1.0f;   // self-loop contribution
}

__global__ void k_deg_accum(const int* __restrict__ dst, float* deg) {
    int e = blockIdx.x * 256 + threadIdx.x;
    if (e < N_EDGES) unsafeAtomicAdd(deg + dst[e], 1.0f);
}

__global__ void k_dinv(float* deg) {
    int i = blockIdx.x * 256 + threadIdx.x;
    if (i < N_NODES) deg[i] = rsqrtf(deg[i]);  // deg >= 1 always
}

// ---------------- GEMM1: h1[N,16] = x[N,512] @ W1[512,16] ----------------
// 64 rows per block, 256 threads: thread = (rq = tid>>4 in [0,16), j = tid&15).
// Thread computes rows {base+rq+16s, s=0..3}, column j.
// W1 transposed in LDS: w1t[16][516]; stride 516 -> 2-way bank alias (free),
// 516*4 bytes is 16B-aligned so float4 reads are legal.

__global__ __launch_bounds__(256) void k_gemm1(const float* __restrict__ x,
                                               const float* __restrict__ W1,
                                               float* __restrict__ h1) {
    __shared__ float w1t[HIDDEN][516];
    int tid = threadIdx.x;
    for (int e = tid; e < N_FEAT * HIDDEN; e += 256) {
        int k = e >> 4, j = e & 15;
        w1t[j][k] = W1[e];
    }
    __syncthreads();

    int j = tid & 15;
    int rq = tid >> 4;
    int base = blockIdx.x * 64;

    int r[4];
    const float4* xp[4];
    float4 acc[4];
    #pragma unroll
    for (int s = 0; s < 4; s++) {
        int rr = base + rq + 16 * s;
        r[s] = rr;
        int rc = rr < N_NODES ? rr : N_NODES - 1;  // clamp loads, guard stores
        xp[s] = reinterpret_cast<const float4*>(x + (size_t)rc * N_FEAT);
        acc[s] = make_float4(0.f, 0.f, 0.f, 0.f);
    }

    #pragma unroll 2
    for (int k4 = 0; k4 < N_FEAT / 4; k4++) {
        float4 w = *reinterpret_cast<const float4*>(&w1t[j][k4 * 4]);
        #pragma unroll
        for (int s = 0; s < 4; s++) {
            float4 xv = xp[s][k4];
            acc[s].x += xv.x * w.x;
            acc[s].y += xv.y * w.y;
            acc[s].z += xv.z * w.z;
            acc[s].w += xv.w * w.w;
        }
    }

    #pragma unroll
    for (int s = 0; s < 4; s++) {
        if (r[s] < N_NODES) {
            h1[(size_t)r[s] * HIDDEN + j] =
                acc[s].x + acc[s].y + acc[s].z + acc[s].w;
        }
    }
}

// ---------------- scatter-add layer 1 (16 feats) ----------------

__global__ void k_scatter16(const int* __restrict__ src,
                            const int* __restrict__ dst,
                            const float* __restrict__ dinv,
                            const float* __restrict__ h,
                            float* __restrict__ out) {
    int e = blockIdx.x * 256 + threadIdx.x;
    if (e >= N_EDGES + N_NODES) return;
    int s, d;
    if (e < N_EDGES) { s = src[e]; d = dst[e]; }
    else             { s = d = e - N_EDGES; }
    float nrm = dinv[s] * dinv[d];
    const float4* hp = reinterpret_cast<const float4*>(h + (size_t)s * HIDDEN);
    float* op = out + (size_t)d * HIDDEN;
    #pragma unroll
    for (int q = 0; q < 4; q++) {
        float4 v = hp[q];
        unsafeAtomicAdd(op + q * 4 + 0, v.x * nrm);
        unsafeAtomicAdd(op + q * 4 + 1, v.y * nrm);
        unsafeAtomicAdd(op + q * 4 + 2, v.z * nrm);
        unsafeAtomicAdd(op + q * 4 + 3, v.w * nrm);
    }
}

// ---------------- GEMM2: h2[N,40] = relu(agg1 + b1) @ W2[16,40] ----------------

__global__ __launch_bounds__(256) void k_gemm2(const float* __restrict__ agg1,
                                               const float* __restrict__ b1,
                                               const float* __restrict__ W2,
                                               float* __restrict__ h2) {
    int r = blockIdx.x * 256 + threadIdx.x;
    if (r >= N_NODES) return;
    float a[HIDDEN];
    const float4* ap = reinterpret_cast<const float4*>(agg1 + (size_t)r * HIDDEN);
    #pragma unroll
    for (int q = 0; q < 4; q++) {
        float4 v = ap[q];
        a[q * 4 + 0] = fmaxf(v.x + b1[q * 4 + 0], 0.f);
        a[q * 4 + 1] = fmaxf(v.y + b1[q * 4 + 1], 0.f);
        a[q * 4 + 2] = fmaxf(v.z + b1[q * 4 + 2], 0.f);
        a[q * 4 + 3] = fmaxf(v.w + b1[q * 4 + 3], 0.f);
    }
    float acc[N_CLASSES];
    #pragma unroll
    for (int j = 0; j < N_CLASSES; j++) acc[j] = 0.f;
    #pragma unroll
    for (int kk = 0; kk < HIDDEN; kk++) {
        float av = a[kk];
        #pragma unroll
        for (int j = 0; j < N_CLASSES; j++) {
            acc[j] += av * W2[kk * N_CLASSES + j];  // uniform -> scalar loads
        }
    }
    float4* op = reinterpret_cast<float4*>(h2 + (size_t)r * N_CLASSES);
    #pragma unroll
    for (int q = 0; q < N_CLASSES / 4; q++) {
        op[q] = make_float4(acc[q*4+0], acc[q*4+1], acc[q*4+2], acc[q*4+3]);
    }
}

// ---------------- scatter-add layer 2 (40 feats) ----------------

__global__ void k_scatter40(const int* __restrict__ src,
                            const int* __restrict__ dst,
                            const float* __restrict__ dinv,
                            const float* __restrict__ h,
                            float* __restrict__ out) {
    int e = blockIdx.x * 256 + threadIdx.x;
    if (e >= N_EDGES + N_NODES) return;
    int s, d;
    if (e < N_EDGES) { s = src[e]; d = dst[e]; }
    else             { s = d = e - N_EDGES; }
    float nrm = dinv[s] * dinv[d];
    const float4* hp = reinterpret_cast<const float4*>(h + (size_t)s * N_CLASSES);
    float* op = out + (size_t)d * N_CLASSES;
    #pragma unroll
    for (int q = 0; q < N_CLASSES / 4; q++) {
        float4 v = hp[q];
        unsafeAtomicAdd(op + q * 4 + 0, v.x * nrm);
        unsafeAtomicAdd(op + q * 4 + 1, v.y * nrm);
        unsafeAtomicAdd(op + q * 4 + 2, v.z * nrm);
        unsafeAtomicAdd(op + q * 4 + 3, v.w * nrm);
    }
}

// ---------------- bias + log_softmax (in place on d_out) ----------------

__global__ void k_logsoftmax(float* __restrict__ out, const float* __restrict__ b2) {
    int r = blockIdx.x * 256 + threadIdx.x;
    if (r >= N_NODES) return;
    float v[N_CLASSES];
    float* op = out + (size_t)r * N_CLASSES;
    float m = -1e30f;
    #pragma unroll
    for (int q = 0; q < N_CLASSES / 4; q++) {
        float4 t = reinterpret_cast<const float4*>(op)[q];
        v[q*4+0] = t.x + b2[q*4+0];
        v[q*4+1] = t.y + b2[q*4+1];
        v[q*4+2] = t.z + b2[q*4+2];
        v[q*4+3] = t.w + b2[q*4+3];
    }
    #pragma unroll
    for (int j = 0; j < N_CLASSES; j++) m = fmaxf(m, v[j]);
    float sum = 0.f;
    #pragma unroll
    for (int j = 0; j < N_CLASSES; j++) sum += expf(v[j] - m);
    float l = m + logf(sum);
    float4* ov = reinterpret_cast<float4*>(op);
    #pragma unroll
    for (int q = 0; q < N_CLASSES / 4; q++) {
        ov[q] = make_float4(v[q*4+0] - l, v[q*4+1] - l, v[q*4+2] - l, v[q*4+3] - l);
    }
}

// ---------------- launch ----------------

extern "C" void kernel_launch(void* const* d_in, const int* in_sizes, int n_in,
                              void* d_out, int out_size, void* d_ws, size_t ws_size,
                              hipStream_t stream) {
    const float* x  = (const float*)d_in[0];
    const int*   ei = (const int*)d_in[1];     // int64 in reference -> int32 in harness
    const float* W1 = (const float*)d_in[2];
    const float* b1 = (const float*)d_in[3];
    const float* W2 = (const float*)d_in[4];
    const float* b2 = (const float*)d_in[5];
    const int* src = ei;
    const int* dst = ei + N_EDGES;
    float* out = (float*)d_out;

    // workspace layout (bytes)
    char* ws = (char*)d_ws;
    float* dinv = (float*)(ws + 0);                 // 100000 floats (deg, then rsqrt in place)
    float* h1   = (float*)(ws + 524288);            // 6,400,000 B
    float* agg1 = (float*)(ws + 6924288);           // 6,400,000 B
    float* h2   = (float*)(ws + 13324288);          // 16,000,000 B  (end ~29.3 MB)

    const int nodeBlocks = (N_NODES + 255) / 256;            // 391
    const int edgeBlocks = (N_EDGES + 255) / 256;            // 12500
    const int scatBlocks = (N_EDGES + N_NODES + 255) / 256;  // 12891
    const int gemm1Blocks = (N_NODES + 63) / 64;             // 1563

    // zero accumulators with kernels (ws/d_out are poisoned 0xAA before every launch)
    k_zero<<<(N_NODES * HIDDEN + 255) / 256, 256, 0, stream>>>(agg1, N_NODES * HIDDEN);
    k_zero<<<(N_NODES * N_CLASSES + 255) / 256, 256, 0, stream>>>(out, N_NODES * N_CLASSES);

    k_init_deg<<<nodeBlocks, 256, 0, stream>>>(dinv);
    k_deg_accum<<<edgeBlocks, 256, 0, stream>>>(dst, dinv);
    k_dinv<<<nodeBlocks, 256, 0, stream>>>(dinv);

    k_gemm1<<<gemm1Blocks, 256, 0, stream>>>(x, W1, h1);
    k_scatter16<<<scatBlocks, 256, 0, stream>>>(src, dst, dinv, h1, agg1);
    k_gemm2<<<nodeBlocks, 256, 0, stream>>>(agg1, b1, W2, h2);
    k_scatter40<<<scatBlocks, 256, 0, stream>>>(src, dst, dinv, h2, out);
    k_logsoftmax<<<nodeBlocks, 256, 0, stream>>>(out, b2);
}

// Round 3
// 893.207 us; speedup vs baseline: 11.2486x; 11.2486x over previous
//
#include <hip/hip_runtime.h>

#define N_NODES 100000
#define N_EDGES 3200000
#define N_FEAT 512
#define HIDDEN 16
#define N_CLASSES 40

// ---------------- init / degree ----------------

__global__ void k_zero_int(int* p, int n) {
    int i = blockIdx.x * 256 + threadIdx.x;
    if (i < n) p[i] = 0;
}

// count in-edges per dst; ord[e] = this edge's ordinal among its dst's edges
__global__ void k_count(const int* __restrict__ dst, int* __restrict__ cnt,
                        int* __restrict__ ord) {
    int e = blockIdx.x * 256 + threadIdx.x;
    if (e < N_EDGES) ord[e] = atomicAdd(cnt + dst[e], 1);
}

__global__ void k_dinv(const int* __restrict__ cnt, float* __restrict__ dinv) {
    int i = blockIdx.x * 256 + threadIdx.x;
    if (i < N_NODES) dinv[i] = rsqrtf((float)(cnt[i] + 1));  // +1 self-loop
}

// exclusive scan of cnt -> row_start, single block of 1024 threads
__global__ __launch_bounds__(1024) void k_scan(const int* __restrict__ cnt,
                                               int* __restrict__ row_start) {
    __shared__ int wsum[16];
    __shared__ int carry_s;
    int tid = threadIdx.x;
    int lane = tid & 63, wv = tid >> 6;
    if (tid == 0) carry_s = 0;
    __syncthreads();
    for (int base = 0; base < N_NODES; base += 1024) {
        int i = base + tid;
        int v = (i < N_NODES) ? cnt[i] : 0;
        int sc = v;  // inclusive wave scan
        #pragma unroll
        for (int off = 1; off < 64; off <<= 1) {
            int t = __shfl_up(sc, off, 64);
            if (lane >= off) sc += t;
        }
        if (lane == 63) wsum[wv] = sc;
        __syncthreads();
        int wpre = 0, chunk_total = 0;
        #pragma unroll
        for (int w = 0; w < 16; ++w) {
            int s = wsum[w];
            if (w < wv) wpre += s;
            chunk_total += s;
        }
        int excl = carry_s + wpre + sc - v;   // carry_s read before update barrier
        if (i < N_NODES) row_start[i] = excl;
        __syncthreads();
        if (tid == 0) carry_s += chunk_total;
        __syncthreads();
    }
    if (tid == 0) row_start[N_NODES] = N_EDGES;
}

// place each edge at row_start[dst] + ord: edge_data = {src, norm}
__global__ void k_build(const int* __restrict__ src, const int* __restrict__ dst,
                        const int* __restrict__ ord, const int* __restrict__ row_start,
                        const float* __restrict__ dinv, int2* __restrict__ edge_data) {
    int e = blockIdx.x * 256 + threadIdx.x;
    if (e >= N_EDGES) return;
    int s = src[e], d = dst[e];
    int slot = row_start[d] + ord[e];
    float nrm = dinv[s] * dinv[d];
    edge_data[slot] = make_int2(s, __float_as_int(nrm));
}

// ---------------- GEMM1: h1[N,16] = x[N,512] @ W1[512,16] ----------------

__global__ __launch_bounds__(256) void k_gemm1(const float* __restrict__ x,
                                               const float* __restrict__ W1,
                                               float* __restrict__ h1) {
    __shared__ float w1t[HIDDEN][516];
    int tid = threadIdx.x;
    for (int e = tid; e < N_FEAT * HIDDEN; e += 256) {
        int k = e >> 4, j = e & 15;
        w1t[j][k] = W1[e];
    }
    __syncthreads();

    int j = tid & 15;
    int rq = tid >> 4;
    int base = blockIdx.x * 64;

    int r[4];
    const float4* xp[4];
    float4 acc[4];
    #pragma unroll
    for (int s = 0; s < 4; s++) {
        int rr = base + rq + 16 * s;
        r[s] = rr;
        int rc = rr < N_NODES ? rr : N_NODES - 1;
        xp[s] = reinterpret_cast<const float4*>(x + (size_t)rc * N_FEAT);
        acc[s] = make_float4(0.f, 0.f, 0.f, 0.f);
    }

    #pragma unroll 2
    for (int k4 = 0; k4 < N_FEAT / 4; k4++) {
        float4 w = *reinterpret_cast<const float4*>(&w1t[j][k4 * 4]);
        #pragma unroll
        for (int s = 0; s < 4; s++) {
            float4 xv = xp[s][k4];
            acc[s].x += xv.x * w.x;
            acc[s].y += xv.y * w.y;
            acc[s].z += xv.z * w.z;
            acc[s].w += xv.w * w.w;
        }
    }

    #pragma unroll
    for (int s = 0; s < 4; s++) {
        if (r[s] < N_NODES) {
            h1[(size_t)r[s] * HIDDEN + j] =
                acc[s].x + acc[s].y + acc[s].z + acc[s].w;
        }
    }
}

// ---------------- CSR aggregation over 16 features ----------------
// 16 threads per node (group), blockDim 256 => 16 nodes/block.
// Per edge: 16-lane coalesced 64B row gather + 8B broadcast of {src,norm}.

template <bool RELU>
__global__ __launch_bounds__(256) void k_agg16(const int2* __restrict__ edge_data,
                                               const int* __restrict__ row_start,
                                               const float* __restrict__ dinv,
                                               const float* __restrict__ h,
                                               const float* __restrict__ bias,
                                               float* __restrict__ out) {
    int g = threadIdx.x >> 4, j = threadIdx.x & 15;
    int node = blockIdx.x * 16 + g;
    if (node >= N_NODES) return;
    int beg = row_start[node], end = row_start[node + 1];
    float ds = dinv[node];
    float acc = h[(size_t)node * HIDDEN + j] * (ds * ds);  // self loop
    for (int i = beg; i < end; ++i) {
        int2 ed = edge_data[i];
        acc += h[(size_t)ed.x * HIDDEN + j] * __int_as_float(ed.y);
    }
    if (RELU) acc = fmaxf(acc + bias[j], 0.f);
    out[(size_t)node * HIDDEN + j] = acc;
}

// ---------------- final: out = agg2 @ W2 + b2, log_softmax ----------------

__global__ __launch_bounds__(256) void k_out(const float* __restrict__ agg2,
                                             const float* __restrict__ W2,
                                             const float* __restrict__ b2,
                                             float* __restrict__ out) {
    int r = blockIdx.x * 256 + threadIdx.x;
    if (r >= N_NODES) return;
    float a[HIDDEN];
    const float4* ap = reinterpret_cast<const float4*>(agg2 + (size_t)r * HIDDEN);
    #pragma unroll
    for (int q = 0; q < 4; q++) {
        float4 v = ap[q];
        a[q * 4 + 0] = v.x; a[q * 4 + 1] = v.y;
        a[q * 4 + 2] = v.z; a[q * 4 + 3] = v.w;
    }
    float acc[N_CLASSES];
    #pragma unroll
    for (int jj = 0; jj < N_CLASSES; jj++) acc[jj] = b2[jj];
    #pragma unroll
    for (int kk = 0; kk < HIDDEN; kk++) {
        float av = a[kk];
        #pragma unroll
        for (int jj = 0; jj < N_CLASSES; jj++)
            acc[jj] += av * W2[kk * N_CLASSES + jj];  // uniform -> scalar loads
    }
    float m = -1e30f;
    #pragma unroll
    for (int jj = 0; jj < N_CLASSES; jj++) m = fmaxf(m, acc[jj]);
    float sum = 0.f;
    #pragma unroll
    for (int jj = 0; jj < N_CLASSES; jj++) sum += __expf(acc[jj] - m);
    float l = m + __logf(sum);
    float4* op = reinterpret_cast<float4*>(out + (size_t)r * N_CLASSES);
    #pragma unroll
    for (int q = 0; q < N_CLASSES / 4; q++) {
        op[q] = make_float4(acc[q*4+0] - l, acc[q*4+1] - l,
                            acc[q*4+2] - l, acc[q*4+3] - l);
    }
}

// ---------------- launch ----------------

extern "C" void kernel_launch(void* const* d_in, const int* in_sizes, int n_in,
                              void* d_out, int out_size, void* d_ws, size_t ws_size,
                              hipStream_t stream) {
    const float* x  = (const float*)d_in[0];
    const int*   ei = (const int*)d_in[1];   // int64 ref -> int32 in harness
    const float* W1 = (const float*)d_in[2];
    const float* b1 = (const float*)d_in[3];
    const float* W2 = (const float*)d_in[4];
    const float* b2 = (const float*)d_in[5];
    const int* src = ei;
    const int* dst = ei + N_EDGES;
    float* out = (float*)d_out;

    // workspace layout (256B-aligned, ~59 MB total)
    char* ws = (char*)d_ws;
    size_t off = 0;
    auto alloc = [&](size_t bytes) {
        size_t o = off; off = (off + bytes + 255) & ~(size_t)255; return o;
    };
    float* dinv      = (float*)(ws + alloc(sizeof(float) * N_NODES));
    int*   cnt       = (int*)  (ws + alloc(sizeof(int) * N_NODES));
    int*   row_start = (int*)  (ws + alloc(sizeof(int) * (N_NODES + 1)));
    int*   ord       = (int*)  (ws + alloc(sizeof(int) * N_EDGES));
    int2*  edge_data = (int2*) (ws + alloc(sizeof(int2) * N_EDGES));
    float* h1        = (float*)(ws + alloc(sizeof(float) * N_NODES * HIDDEN));
    float* rbuf      = (float*)(ws + alloc(sizeof(float) * N_NODES * HIDDEN));
    float* agg2      = (float*)(ws + alloc(sizeof(float) * N_NODES * HIDDEN));

    const int nodeBlocks  = (N_NODES + 255) / 256;   // 391
    const int edgeBlocks  = (N_EDGES + 255) / 256;   // 12500
    const int gemm1Blocks = (N_NODES + 63) / 64;     // 1563
    const int aggBlocks   = (N_NODES + 15) / 16;     // 6250

    k_zero_int<<<nodeBlocks, 256, 0, stream>>>(cnt, N_NODES);
    k_count<<<edgeBlocks, 256, 0, stream>>>(dst, cnt, ord);
    k_dinv<<<nodeBlocks, 256, 0, stream>>>(cnt, dinv);
    k_scan<<<1, 1024, 0, stream>>>(cnt, row_start);
    k_build<<<edgeBlocks, 256, 0, stream>>>(src, dst, ord, row_start, dinv, edge_data);

    k_gemm1<<<gemm1Blocks, 256, 0, stream>>>(x, W1, h1);
    k_agg16<true><<<aggBlocks, 256, 0, stream>>>(edge_data, row_start, dinv, h1, b1, rbuf);
    k_agg16<false><<<aggBlocks, 256, 0, stream>>>(edge_data, row_start, dinv, rbuf, nullptr, agg2);
    k_out<<<nodeBlocks, 256, 0, stream>>>(agg2, W2, b2, out);
}

// Round 4
// 682.056 us; speedup vs baseline: 14.7310x; 1.3096x over previous
//
#include <hip/hip_runtime.h>

#define N_NODES 100000
#define N_EDGES 3200000
#define N_FEAT 512
#define HIDDEN 16
#define N_CLASSES 40

#define SCAN_BLOCKS 98   // ceil(100000/1024)

// ---------------- init / degree ----------------

__global__ void k_zero_int(int* p, int n) {
    int i = blockIdx.x * 256 + threadIdx.x;
    if (i < n) p[i] = 0;
}

// count in-edges per dst; ord[e] = this edge's ordinal among its dst's edges
__global__ void k_count(const int* __restrict__ dst, int* __restrict__ cnt,
                        int* __restrict__ ord) {
    int e = blockIdx.x * 256 + threadIdx.x;
    if (e < N_EDGES) ord[e] = atomicAdd(cnt + dst[e], 1);
}

__global__ void k_dinv(const int* __restrict__ cnt, float* __restrict__ dinv) {
    int i = blockIdx.x * 256 + threadIdx.x;
    if (i < N_NODES) dinv[i] = rsqrtf((float)(cnt[i] + 1));  // +1 self-loop
}

// ---------------- 3-phase exclusive scan of cnt -> row_start ----------------

__global__ __launch_bounds__(1024) void k_scan_a(const int* __restrict__ cnt,
                                                 int* __restrict__ bsum) {
    int tid = threadIdx.x;
    int i = blockIdx.x * 1024 + tid;
    int v = (i < N_NODES) ? cnt[i] : 0;
    #pragma unroll
    for (int off = 32; off >= 1; off >>= 1) v += __shfl_xor(v, off, 64);
    __shared__ int ws[16];
    if ((tid & 63) == 0) ws[tid >> 6] = v;
    __syncthreads();
    if (tid == 0) {
        int s = 0;
        #pragma unroll
        for (int w = 0; w < 16; w++) s += ws[w];
        bsum[blockIdx.x] = s;
    }
}

__global__ __launch_bounds__(128) void k_scan_b(const int* __restrict__ bsum,
                                                int* __restrict__ boff) {
    int tid = threadIdx.x;
    int lane = tid & 63, wv = tid >> 6;
    int v = (tid < SCAN_BLOCKS) ? bsum[tid] : 0;
    int sc = v;
    #pragma unroll
    for (int off = 1; off < 64; off <<= 1) {
        int t = __shfl_up(sc, off, 64);
        if (lane >= off) sc += t;
    }
    __shared__ int wsum[2];
    if (lane == 63) wsum[wv] = sc;
    __syncthreads();
    int pre = (wv == 1) ? wsum[0] : 0;
    if (tid < SCAN_BLOCKS) boff[tid] = pre + sc - v;  // exclusive
}

__global__ __launch_bounds__(1024) void k_scan_c(const int* __restrict__ cnt,
                                                 const int* __restrict__ boff,
                                                 int* __restrict__ row_start) {
    int tid = threadIdx.x;
    int i = blockIdx.x * 1024 + tid;
    int lane = tid & 63, wv = tid >> 6;
    int v = (i < N_NODES) ? cnt[i] : 0;
    int sc = v;
    #pragma unroll
    for (int off = 1; off < 64; off <<= 1) {
        int t = __shfl_up(sc, off, 64);
        if (lane >= off) sc += t;
    }
    __shared__ int wsum[16];
    if (lane == 63) wsum[wv] = sc;
    __syncthreads();
    int pre = 0;
    #pragma unroll
    for (int w = 0; w < 16; w++) pre += (w < wv) ? wsum[w] : 0;
    int excl = boff[blockIdx.x] + pre + sc - v;
    if (i < N_NODES) row_start[i] = excl;
    if (i == N_NODES) row_start[N_NODES] = N_EDGES;
}

// place each edge at row_start[dst] + ord: edge_data = {src, norm}
__global__ void k_build(const int* __restrict__ src, const int* __restrict__ dst,
                        const int* __restrict__ ord, const int* __restrict__ row_start,
                        const float* __restrict__ dinv, int2* __restrict__ edge_data) {
    int e = blockIdx.x * 256 + threadIdx.x;
    if (e >= N_EDGES) return;
    int s = src[e], d = dst[e];
    int slot = row_start[d] + ord[e];
    float nrm = dinv[s] * dinv[d];
    edge_data[slot] = make_int2(s, __float_as_int(nrm));
}

// ---------------- GEMM1: h1[N,16] = x[N,512] @ W1[512,16] ----------------
// 256 rows/block, thread owns one row. K chunked by 32, staged dense in LDS
// ([256][36] pad -> bank-balanced b128 reads/writes). W1 read at wave-uniform
// indices -> scalar-cache s_load, off the VMEM pipe.

#define KC 32
#define LDSW 36

__global__ __launch_bounds__(256) void k_gemm1(const float* __restrict__ x,
                                               const float* __restrict__ W1,
                                               float* __restrict__ h1) {
    __shared__ float xs[256 * LDSW];
    int tid = threadIdx.x;
    int row = blockIdx.x * 256 + tid;

    float acc[HIDDEN];
    #pragma unroll
    for (int j = 0; j < HIDDEN; j++) acc[j] = 0.f;

    int s_sub = tid >> 3;  // 0..31 staging row-sub
    int s_k4  = tid & 7;   // 0..7  staging k4

    for (int kc = 0; kc < N_FEAT; kc += KC) {
        __syncthreads();  // previous chunk's reads done before overwrite
        #pragma unroll
        for (int l = 0; l < 8; l++) {
            int srow = s_sub + l * 32;
            int grow = blockIdx.x * 256 + srow;
            int gr = grow < N_NODES ? grow : N_NODES - 1;  // clamp
            float4 v = *reinterpret_cast<const float4*>(
                x + (size_t)gr * N_FEAT + kc + s_k4 * 4);
            *reinterpret_cast<float4*>(&xs[srow * LDSW + s_k4 * 4]) = v;
        }
        __syncthreads();

        const float* Wc = W1 + kc * HIDDEN;  // wave-uniform
        #pragma unroll
        for (int k4 = 0; k4 < 8; k4++) {
            float4 xv = *reinterpret_cast<const float4*>(&xs[tid * LDSW + k4 * 4]);
            const float* w0 = Wc + (k4 * 4 + 0) * HIDDEN;
            const float* w1 = Wc + (k4 * 4 + 1) * HIDDEN;
            const float* w2 = Wc + (k4 * 4 + 2) * HIDDEN;
            const float* w3 = Wc + (k4 * 4 + 3) * HIDDEN;
            #pragma unroll
            for (int j = 0; j < HIDDEN; j++) {
                acc[j] += xv.x * w0[j];
                acc[j] += xv.y * w1[j];
                acc[j] += xv.z * w2[j];
                acc[j] += xv.w * w3[j];
            }
        }
    }

    if (row < N_NODES) {
        float4* op = reinterpret_cast<float4*>(h1 + (size_t)row * HIDDEN);
        #pragma unroll
        for (int q = 0; q < 4; q++)
            op[q] = make_float4(acc[q*4+0], acc[q*4+1], acc[q*4+2], acc[q*4+3]);
    }
}

// ---------------- CSR aggregation over 16 features ----------------
// 16 threads per node, 16 nodes/block. 4-wide edge unroll for MLP.

template <bool RELU>
__global__ __launch_bounds__(256) void k_agg16(const int2* __restrict__ edge_data,
                                               const int* __restrict__ row_start,
                                               const float* __restrict__ dinv,
                                               const float* __restrict__ h,
                                               const float* __restrict__ bias,
                                               float* __restrict__ out) {
    int g = threadIdx.x >> 4, j = threadIdx.x & 15;
    int node = blockIdx.x * 16 + g;
    if (node >= N_NODES) return;
    int beg = row_start[node], end = row_start[node + 1];
    float ds = dinv[node];
    float acc = h[(size_t)node * HIDDEN + j] * (ds * ds);  // self loop
    int i = beg;
    for (; i + 3 < end; i += 4) {
        int2 e0 = edge_data[i + 0];
        int2 e1 = edge_data[i + 1];
        int2 e2 = edge_data[i + 2];
        int2 e3 = edge_data[i + 3];
        float v0 = h[(size_t)e0.x * HIDDEN + j];
        float v1 = h[(size_t)e1.x * HIDDEN + j];
        float v2 = h[(size_t)e2.x * HIDDEN + j];
        float v3 = h[(size_t)e3.x * HIDDEN + j];
        acc += v0 * __int_as_float(e0.y);
        acc += v1 * __int_as_float(e1.y);
        acc += v2 * __int_as_float(e2.y);
        acc += v3 * __int_as_float(e3.y);
    }
    for (; i < end; ++i) {
        int2 ed = edge_data[i];
        acc += h[(size_t)ed.x * HIDDEN + j] * __int_as_float(ed.y);
    }
    if (RELU) acc = fmaxf(acc + bias[j], 0.f);
    out[(size_t)node * HIDDEN + j] = acc;
}

// ---------------- final: out = agg2 @ W2 + b2, log_softmax ----------------

__global__ __launch_bounds__(256) void k_out(const float* __restrict__ agg2,
                                             const float* __restrict__ W2,
                                             const float* __restrict__ b2,
                                             float* __restrict__ out) {
    int r = blockIdx.x * 256 + threadIdx.x;
    if (r >= N_NODES) return;
    float a[HIDDEN];
    const float4* ap = reinterpret_cast<const float4*>(agg2 + (size_t)r * HIDDEN);
    #pragma unroll
    for (int q = 0; q < 4; q++) {
        float4 v = ap[q];
        a[q * 4 + 0] = v.x; a[q * 4 + 1] = v.y;
        a[q * 4 + 2] = v.z; a[q * 4 + 3] = v.w;
    }
    float acc[N_CLASSES];
    #pragma unroll
    for (int jj = 0; jj < N_CLASSES; jj++) acc[jj] = b2[jj];
    #pragma unroll
    for (int kk = 0; kk < HIDDEN; kk++) {
        float av = a[kk];
        #pragma unroll
        for (int jj = 0; jj < N_CLASSES; jj++)
            acc[jj] += av * W2[kk * N_CLASSES + jj];  // uniform -> scalar loads
    }
    float m = -1e30f;
    #pragma unroll
    for (int jj = 0; jj < N_CLASSES; jj++) m = fmaxf(m, acc[jj]);
    float sum = 0.f;
    #pragma unroll
    for (int jj = 0; jj < N_CLASSES; jj++) sum += __expf(acc[jj] - m);
    float l = m + __logf(sum);
    float4* op = reinterpret_cast<float4*>(out + (size_t)r * N_CLASSES);
    #pragma unroll
    for (int q = 0; q < N_CLASSES / 4; q++) {
        op[q] = make_float4(acc[q*4+0] - l, acc[q*4+1] - l,
                            acc[q*4+2] - l, acc[q*4+3] - l);
    }
}

// ---------------- launch ----------------

extern "C" void kernel_launch(void* const* d_in, const int* in_sizes, int n_in,
                              void* d_out, int out_size, void* d_ws, size_t ws_size,
                              hipStream_t stream) {
    const float* x  = (const float*)d_in[0];
    const int*   ei = (const int*)d_in[1];   // int64 ref -> int32 in harness
    const float* W1 = (const float*)d_in[2];
    const float* b1 = (const float*)d_in[3];
    const float* W2 = (const float*)d_in[4];
    const float* b2 = (const float*)d_in[5];
    const int* src = ei;
    const int* dst = ei + N_EDGES;
    float* out = (float*)d_out;

    // workspace layout (256B-aligned, ~59 MB total)
    char* ws = (char*)d_ws;
    size_t off = 0;
    auto alloc = [&](size_t bytes) {
        size_t o = off; off = (off + bytes + 255) & ~(size_t)255; return o;
    };
    float* dinv      = (float*)(ws + alloc(sizeof(float) * N_NODES));
    int*   cnt       = (int*)  (ws + alloc(sizeof(int) * N_NODES));
    int*   row_start = (int*)  (ws + alloc(sizeof(int) * (N_NODES + 1)));
    int*   ord       = (int*)  (ws + alloc(sizeof(int) * N_EDGES));
    int2*  edge_data = (int2*) (ws + alloc(sizeof(int2) * N_EDGES));
    float* h1        = (float*)(ws + alloc(sizeof(float) * N_NODES * HIDDEN));
    float* rbuf      = (float*)(ws + alloc(sizeof(float) * N_NODES * HIDDEN));
    float* agg2      = (float*)(ws + alloc(sizeof(float) * N_NODES * HIDDEN));
    int*   bsum      = (int*)  (ws + alloc(sizeof(int) * SCAN_BLOCKS));
    int*   boff      = (int*)  (ws + alloc(sizeof(int) * SCAN_BLOCKS));

    const int nodeBlocks  = (N_NODES + 255) / 256;   // 391
    const int edgeBlocks  = (N_EDGES + 255) / 256;   // 12500
    const int aggBlocks   = (N_NODES + 15) / 16;     // 6250

    k_zero_int<<<nodeBlocks, 256, 0, stream>>>(cnt, N_NODES);
    k_count<<<edgeBlocks, 256, 0, stream>>>(dst, cnt, ord);
    k_dinv<<<nodeBlocks, 256, 0, stream>>>(cnt, dinv);
    k_scan_a<<<SCAN_BLOCKS, 1024, 0, stream>>>(cnt, bsum);
    k_scan_b<<<1, 128, 0, stream>>>(bsum, boff);
    k_scan_c<<<SCAN_BLOCKS, 1024, 0, stream>>>(cnt, boff, row_start);
    k_build<<<edgeBlocks, 256, 0, stream>>>(src, dst, ord, row_start, dinv, edge_data);

    k_gemm1<<<nodeBlocks, 256, 0, stream>>>(x, W1, h1);
    k_agg16<true><<<aggBlocks, 256, 0, stream>>>(edge_data, row_start, dinv, h1, b1, rbuf);
    k_agg16<false><<<aggBlocks, 256, 0, stream>>>(edge_data, row_start, dinv, rbuf, nullptr, agg2);
    k_out<<<nodeBlocks, 256, 0, stream>>>(agg2, W2, b2, out);
}